// Round 2
// baseline (113.261 us; speedup 1.0000x reference)
//
#include <hip/hip_runtime.h>
#include <math.h>

#define N_ROWS 2048
#define D_DIM 512
#define P_DIM 10

__device__ inline float wave_reduce_f(float v) {
#pragma unroll
  for (int off = 32; off > 0; off >>= 1) v += __shfl_down(v, off, 64);
  return v;
}

__device__ inline double wave_reduce_d(double v) {
#pragma unroll
  for (int off = 32; off > 0; off >>= 1) v += __shfl_down(v, off, 64);
  return v;
}

// Order-preserving f32 -> u32 map (total order, -0 < +0, NaN high).
__device__ inline unsigned f32_sortkey(float v) {
  unsigned u = __float_as_uint(v);
  return (u & 0x80000000u) ? ~u : (u | 0x80000000u);
}

// K1: wave-per-row. Computes post/prior projections and writes UNIQUE u64
// sort keys per column: (sortable_bits << 32) | row. proj staged transposed
// in LDS as [p][k] so lane-stride-1 LDS reads are conflict-free.
__global__ __launch_bounds__(256) void rc_proj_kernel(
    const float* __restrict__ z, const float* __restrict__ g,
    const float* __restrict__ proj, unsigned long long* __restrict__ post_key,
    unsigned long long* __restrict__ prior_key) {
  __shared__ float pl[P_DIM * D_DIM];  // [p][k], 20 KiB
  for (int i = threadIdx.x; i < P_DIM * D_DIM; i += 256) {
    int k = i / P_DIM, p = i - k * P_DIM;
    pl[p * D_DIM + k] = proj[i];
  }
  __syncthreads();
  const int wave = threadIdx.x >> 6, lane = threadIdx.x & 63;
  const int row = blockIdx.x * 4 + wave;
  const float* zr = z + (size_t)row * D_DIM;
  const float* gr = g + (size_t)row * D_DIM;
  float zv[8], gv[8];
#pragma unroll
  for (int m = 0; m < 8; ++m) {  // coalesced: lane-stride-1, 4B/lane
    zv[m] = zr[m * 64 + lane];
    gv[m] = gr[m * 64 + lane];
  }
  float n2 = 0.f;
#pragma unroll
  for (int m = 0; m < 8; ++m) n2 += gv[m] * gv[m];
  float az[P_DIM], ag[P_DIM];
#pragma unroll
  for (int p = 0; p < P_DIM; ++p) { az[p] = 0.f; ag[p] = 0.f; }
#pragma unroll
  for (int m = 0; m < 8; ++m) {
#pragma unroll
    for (int p = 0; p < P_DIM; ++p) {
      float w = pl[p * D_DIM + m * 64 + lane];
      az[p] += zv[m] * w;
      ag[p] += gv[m] * w;
    }
  }
#pragma unroll
  for (int p = 0; p < P_DIM; ++p) {
    az[p] = wave_reduce_f(az[p]);
    ag[p] = wave_reduce_f(ag[p]);
  }
  n2 = wave_reduce_f(n2);
  if (lane == 0) {
    float inv = 1.f / fmaxf(sqrtf(n2), 1e-12f);
    for (int p = 0; p < P_DIM; ++p) {
      post_key[p * N_ROWS + row] =
          ((unsigned long long)f32_sortkey(az[p]) << 32) | (unsigned)row;
      prior_key[p * N_ROWS + row] =
          ((unsigned long long)f32_sortkey(ag[p] * inv) << 32) | (unsigned)row;
    }
  }
}

// K2: rank sort. 20 columns x 8 chunks = 160 blocks x 256 threads; each
// thread owns one element, counts keys smaller than its own (keys unique =>
// exact permutation), decodes the value from the key's high word, and
// scatters sorted[c][rank] = value. The j-loop address is wave-uniform =>
// compiler scalarizes to s_load through the scalar cache (no LDS, no VMEM
// pressure); even as a vector load it's one L1 transaction per iteration.
__global__ __launch_bounds__(256) void rc_rank_kernel(
    const unsigned long long* __restrict__ keys,  // 20 contiguous columns
    float* __restrict__ sorted) {                 // 20 contiguous columns
  const int c = blockIdx.x >> 3;
  const int chunk = blockIdx.x & 7;
  const unsigned long long* kcol = keys + (size_t)c * N_ROWS;
  const int i = chunk * 256 + threadIdx.x;
  const unsigned long long myk = kcol[i];
  int r0 = 0, r1 = 0, r2 = 0, r3 = 0;
#pragma unroll 16
  for (int j = 0; j < N_ROWS; j += 4) {
    r0 += (kcol[j + 0] < myk) ? 1 : 0;
    r1 += (kcol[j + 1] < myk) ? 1 : 0;
    r2 += (kcol[j + 2] < myk) ? 1 : 0;
    r3 += (kcol[j + 3] < myk) ? 1 : 0;
  }
  const int rank = r0 + r1 + r2 + r3;
  unsigned u = (unsigned)(myk >> 32);
  float v = __uint_as_float((u & 0x80000000u) ? (u & 0x7FFFFFFFu) : ~u);
  sorted[(size_t)c * N_ROWS + rank] = v;
}

// K3: per-(column p, variant) closed-form statistics in f64.
// gw*N^2 = 2N*Ss2 + 2*Ss^2 - 8*(Ssa*Sa - Ssb*Sb) + 4*(Sa2^2 - 2*Sab^2 + Sb2^2)
// where s_i = a_i^2 - b_i^2. variant 1 uses b reversed (prior2 = prior1[::-1]).
__global__ __launch_bounds__(256) void rc_stats_kernel(
    const float* __restrict__ post_s, const float* __restrict__ prior_s,
    float* __restrict__ fgw) {
  const int p = blockIdx.x % P_DIM;
  const int variant = blockIdx.x / P_DIM;
  const float* a = post_s + p * N_ROWS;
  const float* b = prior_s + p * N_ROWS;
  double S[10];
#pragma unroll
  for (int t = 0; t < 10; ++t) S[t] = 0.0;
  for (int i = threadIdx.x; i < N_ROWS; i += 256) {
    double av = (double)a[i];
    double bv = (double)(variant ? b[N_ROWS - 1 - i] : b[i]);
    double a2 = av * av, b2 = bv * bv;
    double s = a2 - b2;
    S[0] += s * s;
    S[1] += s;
    S[2] += s * av;
    S[3] += av;
    S[4] += s * bv;
    S[5] += bv;
    S[6] += a2;
    S[7] += av * bv;
    S[8] += b2;
    double d = av - bv;
    S[9] += d * d;
  }
#pragma unroll
  for (int t = 0; t < 10; ++t) S[t] = wave_reduce_d(S[t]);
  __shared__ double sm[4][10];
  const int wave = threadIdx.x >> 6, lane = threadIdx.x & 63;
  if (lane == 0) {
#pragma unroll
    for (int t = 0; t < 10; ++t) sm[wave][t] = S[t];
  }
  __syncthreads();
  if (threadIdx.x == 0) {
    double T[10];
#pragma unroll
    for (int t = 0; t < 10; ++t)
      T[t] = sm[0][t] + sm[1][t] + sm[2][t] + sm[3][t];
    const double nn = (double)N_ROWS;
    double gw = (2.0 * nn * T[0] + 2.0 * T[1] * T[1]
                 - 8.0 * (T[2] * T[3] - T[4] * T[5])
                 + 4.0 * (T[6] * T[6] - 2.0 * T[7] * T[7] + T[8] * T[8]))
                / (nn * nn);
    double w = T[9];
    fgw[blockIdx.x] = (float)(0.9 * w + 0.1 * gw);
  }
}

// K4: out = mean_p min(fgw1[p], fgw2[p])
__global__ void rc_final_kernel(const float* __restrict__ fgw,
                                float* __restrict__ out) {
  if (threadIdx.x == 0 && blockIdx.x == 0) {
    float s = 0.f;
    for (int p = 0; p < P_DIM; ++p) s += fminf(fgw[p], fgw[P_DIM + p]);
    out[0] = s * (1.f / P_DIM);
  }
}

extern "C" void kernel_launch(void* const* d_in, const int* in_sizes, int n_in,
                              void* d_out, int out_size, void* d_ws,
                              size_t ws_size, hipStream_t stream) {
  const float* z = (const float*)d_in[0];
  const float* g = (const float*)d_in[1];
  const float* proj = (const float*)d_in[2];
  float* out = (float*)d_out;
  // Workspace layout (keys for post then prior are contiguous -> K2 treats
  // them as 20 columns in one launch; same for sorted values):
  unsigned long long* post_key = (unsigned long long*)d_ws;   // 20480 u64
  unsigned long long* prior_key = post_key + N_ROWS * P_DIM;  // 20480 u64
  float* post_s = (float*)(prior_key + N_ROWS * P_DIM);       // 20480 f32
  float* prior_s = post_s + N_ROWS * P_DIM;                   // 20480 f32
  float* fgw = prior_s + N_ROWS * P_DIM;                      // 20 f32

  rc_proj_kernel<<<N_ROWS / 4, 256, 0, stream>>>(z, g, proj, post_key,
                                                 prior_key);
  rc_rank_kernel<<<2 * P_DIM * (N_ROWS / 256), 256, 0, stream>>>(post_key,
                                                                 post_s);
  rc_stats_kernel<<<2 * P_DIM, 256, 0, stream>>>(post_s, prior_s, fgw);
  rc_final_kernel<<<1, 64, 0, stream>>>(fgw, out);
}

// Round 3
// 92.340 us; speedup vs baseline: 1.2266x; 1.2266x over previous
//
#include <hip/hip_runtime.h>
#include <math.h>

#define N_ROWS 2048
#define D_DIM 512
#define P_DIM 10

__device__ inline float wave_reduce_f(float v) {
#pragma unroll
  for (int off = 32; off > 0; off >>= 1) v += __shfl_down(v, off, 64);
  return v;
}

__device__ inline double wave_reduce_d(double v) {
#pragma unroll
  for (int off = 32; off > 0; off >>= 1) v += __shfl_down(v, off, 64);
  return v;
}

// Order-preserving f32 -> u32 map (total order, -0 < +0, NaN high).
__device__ inline unsigned f32_sortkey(float v) {
  unsigned u = __float_as_uint(v);
  return (u & 0x80000000u) ? ~u : (u | 0x80000000u);
}

// K1: wave-per-row. Computes post/prior projections and writes UNIQUE u64
// sort keys per column: (sortable_bits << 32) | row. proj staged transposed
// in LDS as [p][k] so lane-stride-1 LDS reads are conflict-free.
__global__ __launch_bounds__(256) void rc_proj_kernel(
    const float* __restrict__ z, const float* __restrict__ g,
    const float* __restrict__ proj, unsigned long long* __restrict__ post_key,
    unsigned long long* __restrict__ prior_key) {
  __shared__ float pl[P_DIM * D_DIM];  // [p][k], 20 KiB
  for (int i = threadIdx.x; i < P_DIM * D_DIM; i += 256) {
    int k = i / P_DIM, p = i - k * P_DIM;
    pl[p * D_DIM + k] = proj[i];
  }
  __syncthreads();
  const int wave = threadIdx.x >> 6, lane = threadIdx.x & 63;
  const int row = blockIdx.x * 4 + wave;
  const float* zr = z + (size_t)row * D_DIM;
  const float* gr = g + (size_t)row * D_DIM;
  float zv[8], gv[8];
#pragma unroll
  for (int m = 0; m < 8; ++m) {  // coalesced: lane-stride-1, 4B/lane
    zv[m] = zr[m * 64 + lane];
    gv[m] = gr[m * 64 + lane];
  }
  float n2 = 0.f;
#pragma unroll
  for (int m = 0; m < 8; ++m) n2 += gv[m] * gv[m];
  float az[P_DIM], ag[P_DIM];
#pragma unroll
  for (int p = 0; p < P_DIM; ++p) { az[p] = 0.f; ag[p] = 0.f; }
#pragma unroll
  for (int m = 0; m < 8; ++m) {
#pragma unroll
    for (int p = 0; p < P_DIM; ++p) {
      float w = pl[p * D_DIM + m * 64 + lane];
      az[p] += zv[m] * w;
      ag[p] += gv[m] * w;
    }
  }
#pragma unroll
  for (int p = 0; p < P_DIM; ++p) {
    az[p] = wave_reduce_f(az[p]);
    ag[p] = wave_reduce_f(ag[p]);
  }
  n2 = wave_reduce_f(n2);
  if (lane == 0) {
    float inv = 1.f / fmaxf(sqrtf(n2), 1e-12f);
    for (int p = 0; p < P_DIM; ++p) {
      post_key[p * N_ROWS + row] =
          ((unsigned long long)f32_sortkey(az[p]) << 32) | (unsigned)row;
      prior_key[p * N_ROWS + row] =
          ((unsigned long long)f32_sortkey(ag[p] * inv) << 32) | (unsigned)row;
    }
  }
}

// K2: rank sort, LDS edition. 20 columns x 32 chunks = 640 single-wave
// blocks. Each block stages its whole 16 KB key column into LDS with
// coalesced dwordx4 loads, then each thread counts keys < its own via
// wave-uniform ds_read_b128 (broadcast, conflict-free, in-order -> the
// compiler software-pipelines with partial lgkmcnt waits). u64 keys are
// unique (row in low bits) so ranks are an exact permutation; 1 compare =
// 1 v_cmp_lt_u64 + 1 carry-add. NO scalar loads anywhere on the hot path
// (round-2 version scalarized to s_load batches and stalled at 8% VALU).
__global__ __launch_bounds__(64) void rc_rank_kernel(
    const unsigned long long* __restrict__ keys,  // 20 contiguous columns
    float* __restrict__ sorted) {                 // 20 contiguous columns
  const int c = blockIdx.x >> 5;
  const int chunk = blockIdx.x & 31;
  const unsigned long long* kcol = keys + (size_t)c * N_ROWS;
  __shared__ unsigned long long sk[N_ROWS];  // 16 KiB
  {
    const ulonglong2* src = (const ulonglong2*)kcol;
    ulonglong2* dst = (ulonglong2*)sk;
#pragma unroll
    for (int t = 0; t < 16; ++t)
      dst[(int)threadIdx.x + t * 64] = src[(int)threadIdx.x + t * 64];
  }
  __syncthreads();
  const int i = chunk * 64 + (int)threadIdx.x;
  const unsigned long long myk = sk[i];
  int r0 = 0, r1 = 0;
  const ulonglong2* sk2 = (const ulonglong2*)sk;
#pragma unroll 8
  for (int j = 0; j < N_ROWS / 2; ++j) {
    ulonglong2 kk = sk2[j];
    r0 += (kk.x < myk) ? 1 : 0;
    r1 += (kk.y < myk) ? 1 : 0;
  }
  const int rank = r0 + r1;
  unsigned u = (unsigned)(myk >> 32);
  float v = __uint_as_float((u & 0x80000000u) ? (u & 0x7FFFFFFFu) : ~u);
  sorted[(size_t)c * N_ROWS + rank] = v;
}

// K3: per-(column p, variant) closed-form statistics in f64.
// gw*N^2 = 2N*Ss2 + 2*Ss^2 - 8*(Ssa*Sa - Ssb*Sb) + 4*(Sa2^2 - 2*Sab^2 + Sb2^2)
// where s_i = a_i^2 - b_i^2. variant 1 uses b reversed (prior2 = prior1[::-1]).
__global__ __launch_bounds__(256) void rc_stats_kernel(
    const float* __restrict__ post_s, const float* __restrict__ prior_s,
    float* __restrict__ fgw) {
  const int p = blockIdx.x % P_DIM;
  const int variant = blockIdx.x / P_DIM;
  const float* a = post_s + p * N_ROWS;
  const float* b = prior_s + p * N_ROWS;
  double S[10];
#pragma unroll
  for (int t = 0; t < 10; ++t) S[t] = 0.0;
  for (int i = threadIdx.x; i < N_ROWS; i += 256) {
    double av = (double)a[i];
    double bv = (double)(variant ? b[N_ROWS - 1 - i] : b[i]);
    double a2 = av * av, b2 = bv * bv;
    double s = a2 - b2;
    S[0] += s * s;
    S[1] += s;
    S[2] += s * av;
    S[3] += av;
    S[4] += s * bv;
    S[5] += bv;
    S[6] += a2;
    S[7] += av * bv;
    S[8] += b2;
    double d = av - bv;
    S[9] += d * d;
  }
#pragma unroll
  for (int t = 0; t < 10; ++t) S[t] = wave_reduce_d(S[t]);
  __shared__ double sm[4][10];
  const int wave = threadIdx.x >> 6, lane = threadIdx.x & 63;
  if (lane == 0) {
#pragma unroll
    for (int t = 0; t < 10; ++t) sm[wave][t] = S[t];
  }
  __syncthreads();
  if (threadIdx.x == 0) {
    double T[10];
#pragma unroll
    for (int t = 0; t < 10; ++t)
      T[t] = sm[0][t] + sm[1][t] + sm[2][t] + sm[3][t];
    const double nn = (double)N_ROWS;
    double gw = (2.0 * nn * T[0] + 2.0 * T[1] * T[1]
                 - 8.0 * (T[2] * T[3] - T[4] * T[5])
                 + 4.0 * (T[6] * T[6] - 2.0 * T[7] * T[7] + T[8] * T[8]))
                / (nn * nn);
    double w = T[9];
    fgw[blockIdx.x] = (float)(0.9 * w + 0.1 * gw);
  }
}

// K4: out = mean_p min(fgw1[p], fgw2[p])
__global__ void rc_final_kernel(const float* __restrict__ fgw,
                                float* __restrict__ out) {
  if (threadIdx.x == 0 && blockIdx.x == 0) {
    float s = 0.f;
    for (int p = 0; p < P_DIM; ++p) s += fminf(fgw[p], fgw[P_DIM + p]);
    out[0] = s * (1.f / P_DIM);
  }
}

extern "C" void kernel_launch(void* const* d_in, const int* in_sizes, int n_in,
                              void* d_out, int out_size, void* d_ws,
                              size_t ws_size, hipStream_t stream) {
  const float* z = (const float*)d_in[0];
  const float* g = (const float*)d_in[1];
  const float* proj = (const float*)d_in[2];
  float* out = (float*)d_out;
  // Workspace layout (keys for post then prior are contiguous -> K2 treats
  // them as 20 columns in one launch; same for sorted values):
  unsigned long long* post_key = (unsigned long long*)d_ws;   // 20480 u64
  unsigned long long* prior_key = post_key + N_ROWS * P_DIM;  // 20480 u64
  float* post_s = (float*)(prior_key + N_ROWS * P_DIM);       // 20480 f32
  float* prior_s = post_s + N_ROWS * P_DIM;                   // 20480 f32
  float* fgw = prior_s + N_ROWS * P_DIM;                      // 20 f32

  rc_proj_kernel<<<N_ROWS / 4, 256, 0, stream>>>(z, g, proj, post_key,
                                                 prior_key);
  rc_rank_kernel<<<2 * P_DIM * (N_ROWS / 64), 64, 0, stream>>>(post_key,
                                                               post_s);
  rc_stats_kernel<<<2 * P_DIM, 256, 0, stream>>>(post_s, prior_s, fgw);
  rc_final_kernel<<<1, 64, 0, stream>>>(fgw, out);
}